// Round 1
// baseline (195.303 us; speedup 1.0000x reference)
//
#include <hip/hip_runtime.h>

// AntiAliasInterpolation2d: depthwise 13x13 Gaussian blur, stride 4.
// in:  (32, 3, 512, 512) fp32
// w:   (3, 1, 13, 13)    fp32  (separable: k2[i][j] = h[i]*h[j], h = row sums)
// out: (32, 3, 128, 128) fp32
//
// Fused separable design: per block, horizontal stride-4 conv of 73 input
// rows into LDS hbuf[73][128], then vertical stride-4 conv producing 16
// output rows. Memory-bound: ~107 MB minimal traffic.

constexpr int N_IMG = 32, CH = 3, H = 512, W = 512;
constexpr int OH = 128, OW = 128;
constexpr int KS = 13, KA = 6, STR = 4;
constexpr int TILE_R = 16;                      // output rows per block
constexpr int IN_ROWS = TILE_R * STR + (KS - STR); // 73 input rows needed

__global__ __launch_bounds__(256)
void aa_interp_kernel(const float* __restrict__ in,
                      const float* __restrict__ wgt,
                      float* __restrict__ out) {
    __shared__ float h[KS];
    __shared__ float hbuf[IN_ROWS][OW];  // 73*128*4 = 37376 B

    const int nc  = blockIdx.y;          // fused (n, c), 0..95
    const int r0  = blockIdx.x * TILE_R; // first output row of this tile
    const int tid = threadIdx.x;

    // Recover the normalized 1D kernel from the 2D weight via row sums:
    // k2[i][j] = g1[i]g1[j]/S^2  =>  sum_j k2[i][j] = g1[i]/S = h[i].
    if (tid < KS) {
        const float* w2 = wgt + (size_t)(nc % CH) * KS * KS + (size_t)tid * KS;
        float s = 0.f;
        #pragma unroll
        for (int j = 0; j < KS; ++j) s += w2[j];
        h[tid] = s;
    }
    __syncthreads();

    const float* inp = in + (size_t)nc * H * W;
    const int gr0 = r0 * STR - KA;       // first (possibly negative) input row

    // Phase 1: horizontal stride-4 conv -> hbuf. 73*128 = 9344 work items.
    for (int idx = tid; idx < IN_ROWS * OW; idx += 256) {
        const int ir = idx >> 7;         // idx / 128
        const int oc = idx & (OW - 1);   // idx % 128
        const int gr = gr0 + ir;
        float acc = 0.f;
        if (gr >= 0 && gr < H) {
            const float* row = inp + (size_t)gr * W;
            const int c0 = oc * STR - KA;
            #pragma unroll
            for (int k = 0; k < KS; ++k) {
                const int cc = c0 + k;
                if (cc >= 0 && cc < W) acc += h[k] * row[cc];
            }
        }
        hbuf[ir][oc] = acc;
    }
    __syncthreads();

    // Phase 2: vertical stride-4 conv -> out. 16*128 = 2048 items, 8/thread.
    float* op = out + (size_t)nc * OH * OW;
    for (int idx = tid; idx < TILE_R * OW; idx += 256) {
        const int orow = idx >> 7;
        const int oc   = idx & (OW - 1);
        float acc = 0.f;
        #pragma unroll
        for (int k = 0; k < KS; ++k)
            acc += h[k] * hbuf[orow * STR + k][oc];
        op[(size_t)(r0 + orow) * OW + oc] = acc;
    }
}

extern "C" void kernel_launch(void* const* d_in, const int* in_sizes, int n_in,
                              void* d_out, int out_size, void* d_ws, size_t ws_size,
                              hipStream_t stream) {
    const float* in  = (const float*)d_in[0];
    const float* wgt = (const float*)d_in[1];
    float* out = (float*)d_out;

    dim3 grid(OH / TILE_R, N_IMG * CH);  // (8, 96) = 768 blocks
    aa_interp_kernel<<<grid, dim3(256), 0, stream>>>(in, wgt, out);
}

// Round 2
// 158.573 us; speedup vs baseline: 1.2316x; 1.2316x over previous
//
#include <hip/hip_runtime.h>

// AntiAliasInterpolation2d: depthwise 13x13 Gaussian blur, stride 4.
// in:  (32, 3, 512, 512) fp32 ; w: (3,1,13,13) fp32 separable ; out: (32,3,128,128)
//
// Fused separable, vectorized. Per block: horizontal stride-4 conv of 41
// input rows into LDS hbuf[41][128] (float4 path: 7 aligned float4 loads
// produce 4 outputs), then vertical stride-4 conv -> 8 output rows.
// TILE_R=8 -> 1536 blocks (6/CU), 21KB LDS -> high occupancy.

constexpr int N_IMG = 32, CH = 3, H = 512, W = 512;
constexpr int OH = 128, OW = 128;
constexpr int KS = 13, KA = 6, STR = 4;
constexpr int TILE_R = 8;                           // output rows per block
constexpr int IN_ROWS = TILE_R * STR + (KS - STR);  // 41 input rows
constexpr int WCH = W / 4;                          // 128 float4 chunks per input row
constexpr int OW4 = OW / 4;                         // 32 float4 chunks per output row

__global__ __launch_bounds__(256)
void aa_interp_kernel(const float* __restrict__ in,
                      const float* __restrict__ wgt,
                      float* __restrict__ out) {
    __shared__ float h[KS];
    __shared__ float4 hbuf[IN_ROWS][OW4];  // 41*32*16 = 20992 B

    const int nc  = blockIdx.y;            // fused (n, c), 0..95
    const int r0  = blockIdx.x * TILE_R;   // first output row of this tile
    const int tid = threadIdx.x;

    // Recover normalized 1D kernel from 2D weight via row sums:
    // k2[i][j] = g1[i]g1[j]/S^2  =>  sum_j k2[i][j] = g1[i]/S = h[i].
    if (tid < KS) {
        const float* w2 = wgt + (size_t)(nc % CH) * KS * KS + (size_t)tid * KS;
        float s = 0.f;
        #pragma unroll
        for (int j = 0; j < KS; ++j) s += w2[j];
        h[tid] = s;
    }
    __syncthreads();

    const float* inp = in + (size_t)nc * H * W;
    const int gr0 = r0 * STR - KA;         // first (possibly negative) input row

    // Phase 1: horizontal stride-4 conv -> hbuf. 41*32 = 1312 float4 items.
    // Item (ir, oc4) produces outputs oc = 4*oc4 + {0..3}; needs input cols
    // [16*oc4 - 6, 16*oc4 + 18] which live in float4 chunks 4*oc4-2 .. 4*oc4+4.
    for (int idx = tid; idx < IN_ROWS * OW4; idx += 256) {
        const int ir  = idx >> 5;          // / 32
        const int oc4 = idx & 31;
        const int gr  = gr0 + ir;
        float4 acc = make_float4(0.f, 0.f, 0.f, 0.f);
        if (gr >= 0 && gr < H) {
            const float4* row = (const float4*)(inp + (size_t)gr * W);
            float v[28];
            #pragma unroll
            for (int q = 0; q < 7; ++q) {
                const int cq = 4 * oc4 - 2 + q;
                float4 c = (cq >= 0 && cq < WCH) ? row[cq]
                                                 : make_float4(0.f, 0.f, 0.f, 0.f);
                v[4 * q + 0] = c.x; v[4 * q + 1] = c.y;
                v[4 * q + 2] = c.z; v[4 * q + 3] = c.w;
            }
            // v[j] holds input col 16*oc4 - 8 + j; output sub-lane s tap k
            // reads col 16*oc4 + 4s - 6 + k  ->  j = 4s + 2 + k  (2..26)
            #pragma unroll
            for (int k = 0; k < KS; ++k) {
                const float hk = h[k];
                acc.x += hk * v[2 + k];
                acc.y += hk * v[6 + k];
                acc.z += hk * v[10 + k];
                acc.w += hk * v[14 + k];
            }
        }
        hbuf[ir][oc4] = acc;
    }
    __syncthreads();

    // Phase 2: vertical stride-4 conv -> out. 8*32 = 256 float4 items.
    float* op = out + (size_t)nc * OH * OW;
    {
        const int orow = tid >> 5;
        const int oc4  = tid & 31;
        float4 acc = make_float4(0.f, 0.f, 0.f, 0.f);
        #pragma unroll
        for (int k = 0; k < KS; ++k) {
            const float hk = h[k];
            float4 t = hbuf[orow * STR + k][oc4];
            acc.x += hk * t.x; acc.y += hk * t.y;
            acc.z += hk * t.z; acc.w += hk * t.w;
        }
        ((float4*)(op + (size_t)(r0 + orow) * OW))[oc4] = acc;
    }
}

extern "C" void kernel_launch(void* const* d_in, const int* in_sizes, int n_in,
                              void* d_out, int out_size, void* d_ws, size_t ws_size,
                              hipStream_t stream) {
    const float* in  = (const float*)d_in[0];
    const float* wgt = (const float*)d_in[1];
    float* out = (float*)d_out;

    dim3 grid(OH / TILE_R, N_IMG * CH);  // (16, 96) = 1536 blocks
    aa_interp_kernel<<<grid, dim3(256), 0, stream>>>(in, wgt, out);
}

// Round 3
// 155.328 us; speedup vs baseline: 1.2574x; 1.0209x over previous
//
#include <hip/hip_runtime.h>

// AntiAliasInterpolation2d: depthwise 13x13 Gaussian blur, stride 4.
// in: (32,3,512,512) fp32 ; w: (3,1,13,13) fp32 separable ; out: (32,3,128,128)
//
// Fused separable. Phase 1: horizontal stride-4 conv, ONE scalar output per
// lane -> the 13-tap window of output col oc lives in aligned float4 chunks
// oc-2..oc+1, so consecutive lanes issue consecutive dwordx4 loads (perfect
// coalescing, 1 KB/wave/instr). Phase 2: vertical stride-4 conv from LDS
// (b128 contiguous reads) -> dwordx4 stores.

constexpr int N_IMG = 32, CH = 3, H = 512, W = 512;
constexpr int OH = 128, OW = 128;
constexpr int KS = 13, KA = 6, STR = 4;
constexpr int TILE_R = 8;                           // output rows per block
constexpr int IN_ROWS = TILE_R * STR + (KS - STR);  // 41 input rows
constexpr int WCH = W / 4;                          // 128 float4 chunks per input row

__global__ __launch_bounds__(256)
void aa_interp_kernel(const float* __restrict__ in,
                      const float* __restrict__ wgt,
                      float* __restrict__ out) {
    __shared__ float hsh[KS];
    __shared__ float hbuf[IN_ROWS][OW];  // 41*128*4 = 20992 B

    const int nc  = blockIdx.y;          // fused (n, c), 0..95
    const int r0  = blockIdx.x * TILE_R; // first output row of this tile
    const int tid = threadIdx.x;

    // Recover normalized 1D kernel from 2D weight via row sums:
    // k2[i][j] = g1[i]g1[j]/S^2  =>  sum_j k2[i][j] = g1[i]/S = h[i].
    if (tid < KS) {
        const float* w2 = wgt + (size_t)(nc % CH) * KS * KS + (size_t)tid * KS;
        float s = 0.f;
        #pragma unroll
        for (int j = 0; j < KS; ++j) s += w2[j];
        hsh[tid] = s;
    }
    __syncthreads();

    float h[KS];                          // taps in registers (broadcast reads)
    #pragma unroll
    for (int k = 0; k < KS; ++k) h[k] = hsh[k];

    const float* inp = in + (size_t)nc * H * W;
    const int gr0 = r0 * STR - KA;       // first (possibly negative) input row

    // Phase 1: horizontal stride-4 conv -> hbuf. 41*128 = 5248 scalar items.
    // ir = idx>>7 is wave-uniform (row check doesn't diverge).
    for (int idx = tid; idx < IN_ROWS * OW; idx += 256) {
        const int ir = idx >> 7;          // / 128
        const int oc = idx & (OW - 1);
        const int gr = gr0 + ir;
        float acc = 0.f;
        if (gr >= 0 && gr < H) {
            const float4* row = (const float4*)(inp + (size_t)gr * W);
            float f[16];                  // cols 4*oc-8 .. 4*oc+7
            #pragma unroll
            for (int q = 0; q < 4; ++q) {
                const int cq  = oc - 2 + q;
                const int cqc = min(max(cq, 0), WCH - 1);  // clamp: no OOB deref
                const float4 c = row[cqc];
                const bool ok = (cq == cqc);
                f[4 * q + 0] = ok ? c.x : 0.f;
                f[4 * q + 1] = ok ? c.y : 0.f;
                f[4 * q + 2] = ok ? c.z : 0.f;
                f[4 * q + 3] = ok ? c.w : 0.f;
            }
            // tap k reads col 4*oc + k - 6 = f[k + 2]
            #pragma unroll
            for (int k = 0; k < KS; ++k) acc += h[k] * f[k + 2];
        }
        hbuf[ir][oc] = acc;
    }
    __syncthreads();

    // Phase 2: vertical stride-4 conv -> out. 8 rows x 32 float4 = 256 items.
    float* op = out + (size_t)nc * OH * OW;
    {
        const int orow = tid >> 5;
        const int oc4  = tid & 31;
        float4 acc = make_float4(0.f, 0.f, 0.f, 0.f);
        #pragma unroll
        for (int k = 0; k < KS; ++k) {
            const float4 t = *(const float4*)&hbuf[orow * STR + k][4 * oc4];
            acc.x += h[k] * t.x; acc.y += h[k] * t.y;
            acc.z += h[k] * t.z; acc.w += h[k] * t.w;
        }
        *((float4*)(op + (size_t)(r0 + orow) * OW) + oc4) = acc;
    }
}

extern "C" void kernel_launch(void* const* d_in, const int* in_sizes, int n_in,
                              void* d_out, int out_size, void* d_ws, size_t ws_size,
                              hipStream_t stream) {
    const float* in  = (const float*)d_in[0];
    const float* wgt = (const float*)d_in[1];
    float* out = (float*)d_out;

    dim3 grid(OH / TILE_R, N_IMG * CH);  // (16, 96) = 1536 blocks
    aa_interp_kernel<<<grid, dim3(256), 0, stream>>>(in, wgt, out);
}

// Round 4
// 149.422 us; speedup vs baseline: 1.3071x; 1.0395x over previous
//
#include <hip/hip_runtime.h>

// AntiAliasInterpolation2d: depthwise 13x13 Gaussian (separable), stride 4.
// in: (32,3,512,512) fp32 ; w: (3,1,13,13) fp32 ; out: (32,3,128,128) fp32
//
// v4: vertical-first streaming. Each thread owns one float4 chunk-column and
// streams its group's 25 input rows ONCE (perfectly coalesced, zero
// redundancy, 25 independent loads -> deep pipelining), accumulating into 4
// output-row accumulators. Result goes to LDS in polyphase layout
// vb[col%4][row][col/4] so the horizontal stride-4 pass reads consecutive
// LDS words per lane (conflict-free). Phase 2: 13 conflict-free b32 reads
// + FMA per output, coalesced scalar stores.

constexpr int CH = 3, H = 512, W = 512;
constexpr int OH = 128, OW = 128;
constexpr int KS = 13, KA = 6, STR = 4;
constexpr int TILE_R = 8;                      // output rows per block
constexpr int GRP = 4;                         // output rows per thread-group
constexpr int G_ROWS = GRP * STR + (KS - STR); // 25 input rows per group
constexpr int WCH = W / 4;                     // 128 float4 chunks per row

__global__ __launch_bounds__(256)
void aa_interp_kernel(const float* __restrict__ in,
                      const float* __restrict__ wgt,
                      float* __restrict__ out) {
    __shared__ float hsh[KS];
    __shared__ float vb[STR][TILE_R][WCH];     // polyphase vertical result, 16 KB

    const int nc  = blockIdx.y;                // fused (n, c), 0..95
    const int r0  = blockIdx.x * TILE_R;       // first output row of tile
    const int tid = threadIdx.x;

    // Normalized 1D kernel = row sums of the 2D outer-product weight.
    if (tid < KS) {
        const float* w2 = wgt + (size_t)(nc % CH) * KS * KS + (size_t)tid * KS;
        float s = 0.f;
        #pragma unroll
        for (int j = 0; j < KS; ++j) s += w2[j];
        hsh[tid] = s;
    }
    __syncthreads();

    float h[KS];
    #pragma unroll
    for (int k = 0; k < KS; ++k) h[k] = hsh[k];

    // ---- Phase 1: vertical stride-4 conv, streaming, bytes-once ----------
    const int g = tid >> 7;                    // row-group 0/1 (orows 4g..4g+3)
    const int c = tid & 127;                   // float4 chunk column
    const float* inp = in + (size_t)nc * H * W;
    const int base = r0 * STR - KA + g * GRP * STR;  // group's first input row

    float4 acc[GRP];
    #pragma unroll
    for (int r = 0; r < GRP; ++r) acc[r] = make_float4(0.f, 0.f, 0.f, 0.f);

    #pragma unroll
    for (int ir = 0; ir < G_ROWS; ++ir) {
        const int row = base + ir;             // wave-uniform bounds check
        float4 v = make_float4(0.f, 0.f, 0.f, 0.f);
        if (row >= 0 && row < H)
            v = ((const float4*)(inp + (size_t)row * W))[c];
        #pragma unroll
        for (int r = 0; r < GRP; ++r) {
            const int k = ir - STR * r;        // compile-time resolved
            if (0 <= k && k < KS) {
                const float hk = h[k];
                acc[r].x += hk * v.x; acc[r].y += hk * v.y;
                acc[r].z += hk * v.z; acc[r].w += hk * v.w;
            }
        }
    }
    #pragma unroll
    for (int r = 0; r < GRP; ++r) {            // conflict-free b32 writes
        const int orow = g * GRP + r;
        vb[0][orow][c] = acc[r].x;
        vb[1][orow][c] = acc[r].y;
        vb[2][orow][c] = acc[r].z;
        vb[3][orow][c] = acc[r].w;
    }
    __syncthreads();

    // ---- Phase 2: horizontal stride-4 conv from polyphase LDS ------------
    // Output col oc, tap k reads col 4*oc - 6 + k = 4*j + p with
    // p = (k+2)&3, j = oc - 2 + ((k+2)>>2)  -> j consecutive per lane.
    float* op = out + (size_t)nc * OH * OW + (size_t)r0 * OW;
    #pragma unroll
    for (int i = 0; i < TILE_R * OW / 256; ++i) {   // 4 outputs per thread
        const int idx  = tid + 256 * i;
        const int orow = idx >> 7;
        const int oc   = idx & (OW - 1);
        float a = 0.f;
        #pragma unroll
        for (int k = 0; k < KS; ++k) {
            const int p = (k + 2) & 3;
            const int j = oc - 2 + ((k + 2) >> 2);
            if (j >= 0 && j < WCH) a += h[k] * vb[p][orow][j];
        }
        op[orow * OW + oc] = a;
    }
}

extern "C" void kernel_launch(void* const* d_in, const int* in_sizes, int n_in,
                              void* d_out, int out_size, void* d_ws, size_t ws_size,
                              hipStream_t stream) {
    const float* in  = (const float*)d_in[0];
    const float* wgt = (const float*)d_in[1];
    float* out = (float*)d_out;

    dim3 grid(OH / TILE_R, 32 * CH);           // (16, 96) = 1536 blocks
    aa_interp_kernel<<<grid, dim3(256), 0, stream>>>(in, wgt, out);
}

// Round 5
// 147.335 us; speedup vs baseline: 1.3256x; 1.0142x over previous
//
#include <hip/hip_runtime.h>

// AntiAliasInterpolation2d: depthwise 13x13 Gaussian (separable), stride 4.
// in: (32,3,512,512) fp32 ; w: (3,1,13,13) fp32 ; out: (32,3,128,128) fp32
//
// v5: vertical-first streaming with UNCONDITIONAL loads. Per-row `if` around
// the global load made vmcnt path-dependent -> compiler emitted vmcnt(0) per
// iteration -> 25 loads serialized at ~700 cyc each (the ~43 us plateau).
// Now: interior tiles run a branch-free 25-load stream (statically countable
// vmcnt, many loads in flight); edge tiles clamp the row address and scale by
// a uniform 0/1 mask. Phase 2 reads a zero-padded polyphase LDS buffer with
// no per-lane predication.

constexpr int CH = 3, H = 512, W = 512;
constexpr int OH = 128, OW = 128;
constexpr int KS = 13, KA = 6, STR = 4;
constexpr int TILE_R = 8;                      // output rows per block
constexpr int GRP = 4;                         // output rows per thread-group
constexpr int G_ROWS = GRP * STR + (KS - STR); // 25 input rows per group
constexpr int WCH = W / 4;                     // 128 float4 chunks per row
constexpr int VBW = WCH + 4;                   // padded chunk width (2 each side)

template <bool EDGE>
__device__ __forceinline__ void vpass(const float* __restrict__ inp, int base,
                                      int c, const float* __restrict__ h,
                                      float4* __restrict__ acc) {
    #pragma unroll
    for (int ir = 0; ir < G_ROWS; ++ir) {
        int row = base + ir;                   // wave-uniform
        float m = 1.f;
        if (EDGE) {
            const int rc = min(max(row, 0), H - 1);
            m = (row == rc) ? 1.f : 0.f;       // uniform 0/1 mask
            row = rc;
        }
        float4 v = ((const float4*)(inp + (size_t)row * W))[c];  // unconditional
        if (EDGE) { v.x *= m; v.y *= m; v.z *= m; v.w *= m; }
        #pragma unroll
        for (int r = 0; r < GRP; ++r) {
            const int k = ir - STR * r;        // compile-time resolved
            if (0 <= k && k < KS) {
                const float hk = h[k];
                acc[r].x += hk * v.x; acc[r].y += hk * v.y;
                acc[r].z += hk * v.z; acc[r].w += hk * v.w;
            }
        }
    }
}

__global__ __launch_bounds__(256)
void aa_interp_kernel(const float* __restrict__ in,
                      const float* __restrict__ wgt,
                      float* __restrict__ out) {
    __shared__ float hsh[KS];
    __shared__ float vb[STR][TILE_R][VBW];     // polyphase + pad, 16.9 KB

    const int nc  = blockIdx.y;                // fused (n, c), 0..95
    const int bx  = blockIdx.x;
    const int r0  = bx * TILE_R;               // first output row of tile
    const int tid = threadIdx.x;

    // Normalized 1D kernel = row sums of the 2D outer-product weight.
    if (tid < KS) {
        const float* w2 = wgt + (size_t)(nc % CH) * KS * KS + (size_t)tid * KS;
        float s = 0.f;
        #pragma unroll
        for (int j = 0; j < KS; ++j) s += w2[j];
        hsh[tid] = s;
    }
    // Zero the 2-chunk pads on both sides of each (phase, row) line.
    if (tid < 128) {
        const int p    = tid >> 5;
        const int orow = (tid >> 2) & 7;
        const int q    = tid & 3;
        vb[p][orow][(q < 2) ? q : 128 + q] = 0.f;   // j+2 in {0,1,130,131}
    }
    __syncthreads();

    float h[KS];
    #pragma unroll
    for (int k = 0; k < KS; ++k) h[k] = hsh[k];

    // ---- Phase 1: vertical stride-4 conv, streaming, bytes-once ----------
    const int g = tid >> 7;                    // row-group 0/1
    const int c = tid & 127;                   // float4 chunk column
    const float* inp = in + (size_t)nc * H * W;
    const int base = r0 * STR - KA + g * GRP * STR;

    float4 acc[GRP];
    #pragma unroll
    for (int r = 0; r < GRP; ++r) acc[r] = make_float4(0.f, 0.f, 0.f, 0.f);

    if (bx != 0 && bx != (OH / TILE_R - 1))
        vpass<false>(inp, base, c, h, acc);    // interior: branch-free stream
    else
        vpass<true>(inp, base, c, h, acc);     // edge: clamp + uniform mask

    #pragma unroll
    for (int r = 0; r < GRP; ++r) {            // conflict-free b32 writes
        const int orow = g * GRP + r;
        vb[0][orow][c + 2] = acc[r].x;
        vb[1][orow][c + 2] = acc[r].y;
        vb[2][orow][c + 2] = acc[r].z;
        vb[3][orow][c + 2] = acc[r].w;
    }
    __syncthreads();

    // ---- Phase 2: horizontal stride-4 conv from padded polyphase LDS -----
    // Output col oc, tap k reads col 4*oc-6+k = chunk j = oc-2+((k+2)>>2),
    // phase p = (k+2)&3; padded index j+2 = oc + ((k+2)>>2). No predication.
    float* op = out + (size_t)nc * OH * OW + (size_t)r0 * OW;
    #pragma unroll
    for (int i = 0; i < TILE_R * OW / 256; ++i) {   // 4 outputs per thread
        const int idx  = tid + 256 * i;
        const int orow = idx >> 7;
        const int oc   = idx & (OW - 1);
        float a = 0.f;
        #pragma unroll
        for (int k = 0; k < KS; ++k)
            a += h[k] * vb[(k + 2) & 3][orow][oc + ((k + 2) >> 2)];
        op[orow * OW + oc] = a;
    }
}

extern "C" void kernel_launch(void* const* d_in, const int* in_sizes, int n_in,
                              void* d_out, int out_size, void* d_ws, size_t ws_size,
                              hipStream_t stream) {
    const float* in  = (const float*)d_in[0];
    const float* wgt = (const float*)d_in[1];
    float* out = (float*)d_out;

    dim3 grid(OH / TILE_R, 32 * CH);           // (16, 96) = 1536 blocks
    aa_interp_kernel<<<grid, dim3(256), 0, stream>>>(in, wgt, out);
}